// Round 6
// baseline (175.989 us; speedup 1.0000x reference)
//
#include <hip/hip_runtime.h>

#define N_NODES 50000
#define N_EDGES 800000
#define HEADS 8
#define NEG_SLOPE 0.2f
#define EPS 1e-16f
#define NBUCK 782            // ceil(50000/64) buckets of 64 dst nodes
#define BNODES 64
#define BCAP 1312            // bucket capacity (load ~Poisson(1023); +9 sigma)
#define GEMMB 782            // gemm blocks (64 rows each)
#define BINB 250             // bin blocks (placed FIRST in the grid)
#define EPB 3200             // 800000 / 250 edges per bin block
#define LOG2E 1.4426950408889634f

// bf16x2 pack/unpack (RNE), exact unpack
__device__ inline unsigned int f2_to_bf2(float a, float b) {
    unsigned int ua = __float_as_uint(a);
    unsigned int ub = __float_as_uint(b);
    ua += 0x7fff + ((ua >> 16) & 1);
    ub += 0x7fff + ((ub >> 16) & 1);
    return (ua >> 16) | (ub & 0xffff0000u);
}
__device__ inline float2 bf2_to_f2(unsigned int u) {
    return make_float2(__uint_as_float(u << 16),
                       __uint_as_float(u & 0xffff0000u));
}

// LDS union: gemm path uses xs (32 KB); bin path uses b (25.3 KB).
union SMem {
    float xs[128 * 64];                   // 32 KB, [k][node]
    struct {
        unsigned int srt[EPB];            // 12.8 KB
        int hist[NBUCK];
        int base[NBUCK];
        int cur[NBUCK];
        int gbase[NBUCK];                 // 12.5 KB
        int wsum[8];
    } b;
};

// ---------------------------------------------------------------------------
// Fused kernel, 512 threads/block. Blocks [0, BINB) bin edges; blocks
// [BINB, BINB+GEMMB) run the x@W GEMM (+ logit epilogue, bf16 pack).
// r5 lesson: at 256thr/4 waves the compiler's unpipelined load->wait->FMA
// k-loop left VALUBusy at 28% (manual reg-dbuf was folded away, VGPR 48).
// Fix is TLP: 512 thr x acc[4][4] -> 4 blocks/CU = 32 waves/CU (100% occ),
// 8 waves/SIMD cover the W-load latency. Same k-accumulation order ->
// bit-identical h.
// ---------------------------------------------------------------------------
__global__ __launch_bounds__(512, 8) void k_fused(const float* __restrict__ x,
                                                  const float* __restrict__ W,
                                                  const float* __restrict__ att_s,
                                                  const float* __restrict__ att_d,
                                                  const int* __restrict__ ei,
                                                  unsigned int* __restrict__ h_bf,
                                                  float* __restrict__ asrc,
                                                  float* __restrict__ adst,
                                                  int* __restrict__ cnt,
                                                  unsigned int* __restrict__ bin) {
    __shared__ SMem sm;
    const int tid = threadIdx.x;

    if (blockIdx.x >= BINB) {
        // ------------------------- GEMM path -------------------------
        const int row0 = (blockIdx.x - BINB) * 64;

        for (int i = tid; i < 64 * 32; i += 512) {
            const int r = i & 63;
            const int k4 = i >> 6;
            const int row = row0 + r;
            float4 v = make_float4(0.f, 0.f, 0.f, 0.f);
            if (row < N_NODES) v = ((const float4*)x)[row * 32 + k4];
            float* d = sm.xs + (k4 * 4) * 64 + r;   // lane-consecutive writes
            d[0]   = v.x;
            d[64]  = v.y;
            d[128] = v.z;
            d[192] = v.w;
        }
        __syncthreads();

        const int colg = tid & 31;
        const int rowg = tid >> 5;                  // 0..15, 4 rows each
        float acc[4][4];
#pragma unroll
        for (int r = 0; r < 4; ++r)
#pragma unroll
            for (int j = 0; j < 4; ++j) acc[r][j] = 0.f;

#pragma unroll 4
        for (int k = 0; k < 128; ++k) {
            const float4 w = ((const float4*)W)[k * 32 + colg];
            const float4 xa = *(const float4*)(sm.xs + k * 64 + rowg * 4);
            const float xv[4] = {xa.x, xa.y, xa.z, xa.w};
            const float wv[4] = {w.x, w.y, w.z, w.w};
#pragma unroll
            for (int r = 0; r < 4; ++r)
#pragma unroll
                for (int j = 0; j < 4; ++j) acc[r][j] += xv[r] * wv[j];
        }

        const int hd = colg >> 2;
        const float4 asv = ((const float4*)att_s)[colg];
        const float4 adv = ((const float4*)att_d)[colg];
#pragma unroll
        for (int r = 0; r < 4; ++r) {
            const int row = row0 + rowg * 4 + r;
            float ps = acc[r][0] * asv.x + acc[r][1] * asv.y +
                       acc[r][2] * asv.z + acc[r][3] * asv.w;
            float pd = acc[r][0] * adv.x + acc[r][1] * adv.y +
                       acc[r][2] * adv.z + acc[r][3] * adv.w;
            ps += __shfl_xor(ps, 1); ps += __shfl_xor(ps, 2);
            pd += __shfl_xor(pd, 1); pd += __shfl_xor(pd, 2);
            if (row < N_NODES) {
                if ((colg & 3) == 0) {
                    asrc[row * 8 + hd] = ps * LOG2E;   // pre-scale for exp2
                    adst[row * 8 + hd] = pd * LOG2E;
                }
                uint2 p;
                p.x = f2_to_bf2(acc[r][0], acc[r][1]);
                p.y = f2_to_bf2(acc[r][2], acc[r][3]);
                ((uint2*)h_bf)[row * 32 + colg] = p;
            }
        }
    } else {
        // ------------------------- BIN path -------------------------
        const int e0 = blockIdx.x * EPB;
        const int lane = tid & 63;
        const int wid = tid >> 6;                   // 0..7

        for (int b = tid; b < NBUCK; b += 512) sm.b.hist[b] = 0;
        __syncthreads();

        // pass 1: histogram (bucket = dst >> 6)
        for (int i = tid; i < EPB; i += 512)
            atomicAdd(&sm.b.hist[ei[N_EDGES + e0 + i] >> 6], 1);
        __syncthreads();

        // exclusive scan: thread owns buckets 2t..2t+1 (2*512 >= NBUCK),
        // two-level shfl scan of per-thread totals
        const int b2 = tid * 2;
        const int l0 = (b2     < NBUCK) ? sm.b.hist[b2]     : 0;
        const int l1 = (b2 + 1 < NBUCK) ? sm.b.hist[b2 + 1] : 0;
        const int tot = l0 + l1;
        int inc = tot;
#pragma unroll
        for (int off = 1; off < 64; off <<= 1) {
            const int u = __shfl_up(inc, off);
            if (lane >= off) inc += u;
        }
        if (lane == 63) sm.b.wsum[wid] = inc;
        __syncthreads();
        int run = inc - tot;
        for (int w2 = 0; w2 < wid; ++w2) run += sm.b.wsum[w2];
        if (b2     < NBUCK) { sm.b.base[b2]     = run; sm.b.cur[b2]     = run; } run += l0;
        if (b2 + 1 < NBUCK) { sm.b.base[b2 + 1] = run; sm.b.cur[b2 + 1] = run; }
        __syncthreads();

        // pass 2: scatter into sorted LDS
        for (int i = tid; i < EPB; i += 512) {
            const unsigned src = (unsigned)ei[e0 + i];
            const unsigned dst = (unsigned)ei[N_EDGES + e0 + i];
            const int p = atomicAdd(&sm.b.cur[dst >> 6], 1);
            if ((unsigned)p < (unsigned)EPB) sm.b.srt[p] = (dst << 16) | src;
        }
        __syncthreads();

        // reserve global ranges (one atomic per non-empty bucket)
        for (int b = tid; b < NBUCK; b += 512)
            sm.b.gbase[b] = (sm.b.hist[b] > 0) ? atomicAdd(&cnt[b], sm.b.hist[b]) : 0;
        __syncthreads();

        // contiguous run copy-out
        for (int p = tid; p < EPB; p += 512) {
            const unsigned rec = sm.b.srt[p];
            const int b = rec >> 22;
            if (b < NBUCK) {
                const int pos = sm.b.gbase[b] + (p - sm.b.base[b]);
                if ((unsigned)pos < (unsigned)BCAP)
                    bin[(size_t)b * BCAP + pos] = rec;
            }
        }
    }
}

// ---------------------------------------------------------------------------
// Aggregation (round-3 structure, proven 53 us profiled). One block (8
// waves) per bucket; counting sort; uniform clamped depth-16 batches;
// producer/consumer ex via shfl.
// ---------------------------------------------------------------------------
__global__ __launch_bounds__(512) void k_aggr(const unsigned int* __restrict__ h_bf,
                                              const unsigned int* __restrict__ bin,
                                              const int* __restrict__ cnt,
                                              const float* __restrict__ asrc,
                                              const float* __restrict__ adst,
                                              const float* __restrict__ bias,
                                              float* __restrict__ out) {
    __shared__ unsigned int srt[BCAP];    // 5.2 KB
    __shared__ int hist[BNODES], base[BNODES], scn[BNODES];

    const int bkt = blockIdx.x;
    const int tid = threadIdx.x;
    const int wid = tid >> 6;
    const int lane = tid & 63;
    const int hd = lane >> 3;     // consumer head (channels lane*2, lane*2+1)
    const int eslot = lane >> 3;  // producer edge slot 0..7
    const int phead = lane & 7;   // producer head

    const int cntb = min(cnt[bkt], BCAP);
    const unsigned int* seg = bin + (size_t)bkt * BCAP;

    if (tid < BNODES) hist[tid] = 0;
    __syncthreads();

    // single pass: read seg once, rank via LDS atomic, keep in registers
    unsigned int myrec[3];
    int myrank[3];
    int nrec = 0;
    for (int i = tid; i < cntb; i += 512) {
        const unsigned rec = seg[i];
        myrank[nrec] = atomicAdd(&hist[(rec >> 16) & 63], 1);
        myrec[nrec] = rec;
        ++nrec;
    }
    __syncthreads();

    if (tid < BNODES) scn[tid] = hist[tid];
    __syncthreads();
    for (int off = 1; off < BNODES; off <<= 1) {
        int v = 0;
        if (tid < BNODES && tid >= off) v = scn[tid - off];
        __syncthreads();
        if (tid < BNODES) scn[tid] += v;
        __syncthreads();
    }
    if (tid < BNODES) base[tid] = scn[tid] - hist[tid];
    __syncthreads();

    for (int k = 0; k < nrec; ++k) {
        const unsigned rec = myrec[k];
        const int p = base[(rec >> 16) & 63] + myrank[k];
        if ((unsigned)p < (unsigned)BCAP) srt[p] = rec;
    }
    __syncthreads();

    // per-wave node processing: wave wid handles dlocal = wid, wid+8, ...
    for (int dl = wid; dl < BNODES; dl += 8) {
        const int d = bkt * BNODES + dl;
        if (d >= N_NODES) continue;
        const int jb = base[dl];
        const int jn = hist[dl];

        const float adst_h = adst[d * 8 + hd];      // consumer head
        const float adst_p = adst[d * 8 + phead];   // producer head
        const float asrc_self = asrc[d * 8 + hd];
        const float2 hdv = bf2_to_f2(h_bf[d * 64 + lane]);

        float es = asrc_self + adst_h;
        es = fmaxf(es, NEG_SLOPE * es);       // LeakyReLU, slope<1
        const float exs = exp2f(es);          // logits pre-scaled by log2e

        float2 acc = make_float2(0.f, 0.f);
        float den = 0.f;

        for (int j0 = 0; j0 < jn; j0 += 16) {
            // broadcast copies of the 16 src ids (same addr across wave: free)
            int s[16];
#pragma unroll
            for (int i = 0; i < 16; ++i) {
                const int jj = j0 + i;
                s[i] = (int)(srt[jb + ((jj < jn) ? jj : jn - 1)] & 0xffffu);
            }
            // issue all 16 row-gathers early (MLP)
            unsigned int hv[16];
#pragma unroll
            for (int i = 0; i < 16; ++i) hv[i] = h_bf[s[i] * 64 + lane];

            // producer lanes: ex for (edge eslot / eslot+8, head phead)
            const int ia = j0 + eslot;
            const int ib = ia + 8;
            const int sa = (int)(srt[jb + min(ia, jn - 1)] & 0xffffu);
            const int sb = (int)(srt[jb + min(ib, jn - 1)] & 0xffffu);
            float eA = asrc[sa * 8 + phead] + adst_p;
            float eB = asrc[sb * 8 + phead] + adst_p;
            eA = fmaxf(eA, NEG_SLOPE * eA);
            eB = fmaxf(eB, NEG_SLOPE * eB);
            const float exA = (ia < jn) ? exp2f(eA) : 0.f;
            const float exB = (ib < jn) ? exp2f(eB) : 0.f;

#pragma unroll
            for (int i = 0; i < 16; ++i) {
                // producer of (edge i, head hd) is lane ((i&7)<<3) | hd
                const float ex = __shfl((i < 8) ? exA : exB,
                                        ((i & 7) << 3) | hd, 64);
                const float2 hv2 = bf2_to_f2(hv[i]);
                acc.x += ex * hv2.x;
                acc.y += ex * hv2.y;
                den += ex;
            }
        }

        const float dtot = den + exs + EPS;
        const float2 b2 = ((const float2*)bias)[lane];
        float vx = (acc.x + exs * hdv.x) / dtot + b2.x;
        float vy = (acc.y + exs * hdv.y) / dtot + b2.y;
        vx = (vx > 0.f) ? vx : expm1f(vx);
        vy = (vy > 0.f) ? vy : expm1f(vy);
        ((float2*)out)[d * 64 + lane] = make_float2(vx, vy);
    }
}

extern "C" void kernel_launch(void* const* d_in, const int* in_sizes, int n_in,
                              void* d_out, int out_size, void* d_ws, size_t ws_size,
                              hipStream_t stream) {
    const float* x     = (const float*)d_in[0];
    const int*   ei    = (const int*)d_in[1];
    const float* W     = (const float*)d_in[2];
    const float* att_s = (const float*)d_in[3];
    const float* att_d = (const float*)d_in[4];
    const float* bias  = (const float*)d_in[5];
    float* out = (float*)d_out;

    // workspace layout (~20.2 MB)
    unsigned int* h_bf = (unsigned int*)d_ws;                   // 12.8 MB
    float* asrc = (float*)(h_bf + (size_t)N_NODES * 64);        // 1.6 MB
    float* adst = asrc + (size_t)N_NODES * HEADS;               // 1.6 MB
    unsigned int* bin = (unsigned int*)(adst + (size_t)N_NODES * HEADS); // 4.1 MB
    int* cnt = (int*)(bin + (size_t)NBUCK * BCAP);              // 782 ints

    hipMemsetAsync(cnt, 0, NBUCK * sizeof(int), stream);
    k_fused<<<BINB + GEMMB, 512, 0, stream>>>(x, W, att_s, att_d, ei,
                                              h_bf, asrc, adst, cnt, bin);
    k_aggr<<<NBUCK, 512, 0, stream>>>(h_bf, bin, cnt, asrc, adst, bias, out);
}